// Round 2
// baseline (247.431 us; speedup 1.0000x reference)
//
#include <hip/hip_runtime.h>
#include <hip/hip_bf16.h>

// Problem constants (B=4, T=2048, D=1024, NH=8, NKV=1, HD=128)
#define B_ 4
#define T_ 2048
#define D_ 1024
#define NH_ 8
#define HD_ 128

typedef short short8 __attribute__((ext_vector_type(8)));   // 8 bf16 (4 VGPRs) MFMA frag
typedef float floatx4 __attribute__((ext_vector_type(4)));  // MFMA accumulator

#if __has_builtin(__builtin_amdgcn_exp2f)
#define EXP2F __builtin_amdgcn_exp2f
#else
#define EXP2F exp2f
#endif
#if __has_builtin(__builtin_amdgcn_rcpf)
#define RCPF __builtin_amdgcn_rcpf
#else
__device__ __forceinline__ float RCPF(float x) { return 1.f / x; }
#endif

// async global->LDS 16B copy (m97 lever); LDS dest must be wave-uniform base
// + lane*16B, which the GEMM staging pattern satisfies by construction.
#if __has_builtin(__builtin_amdgcn_global_load_lds)
#define G2L(gp, lp)                                                        \
  __builtin_amdgcn_global_load_lds(                                        \
      (const __attribute__((address_space(1))) unsigned int*)(gp),         \
      (__attribute__((address_space(3))) unsigned int*)(lp), 16, 0, 0)
#else
#define G2L(gp, lp) (*(uint4*)(lp) = *(const uint4*)(gp))
#endif

__device__ __forceinline__ unsigned short f2b(float f) {
  union { float fl; unsigned int i; } v; v.fl = f;
  unsigned int r = v.i + 0x7fffu + ((v.i >> 16) & 1u);  // RNE, non-NaN inputs
  return (unsigned short)(r >> 16);
}
// pack two f32 -> two bf16 (round-to-nearest): low16 = a, high16 = b
__device__ __forceinline__ unsigned int pack_bf16(float a, float b) {
  unsigned int ua = __float_as_uint(a) + 0x8000u;
  unsigned int ub = __float_as_uint(b) + 0x8000u;
  return (ua >> 16) | (ub & 0xffff0000u);
}
__device__ __forceinline__ float blo(unsigned int u) { return __uint_as_float(u << 16); }
__device__ __forceinline__ float bhi(unsigned int u) { return __uint_as_float(u & 0xffff0000u); }

// ---------------------------------------------------------------------------
// One-shot f32 -> bf16 convert of x|Wq|Wk|Wv|Wo into a contiguous bf16 blob.
// ---------------------------------------------------------------------------
__global__ __launch_bounds__(256) void cvt_kernel(
    const float* __restrict__ x,  const float* __restrict__ wq,
    const float* __restrict__ wk, const float* __restrict__ wv,
    const float* __restrict__ wo, unsigned short* __restrict__ dst)
{
  size_t i = ((size_t)blockIdx.x * 256 + threadIdx.x) * 8;
  const float* src; size_t off;
  if      (i <  8388608u) { src = x;  off = i; }
  else if (i <  9437184u) { src = wq; off = i - 8388608u; }
  else if (i <  9568256u) { src = wk; off = i - 9437184u; }
  else if (i <  9699328u) { src = wv; off = i - 9568256u; }
  else                    { src = wo; off = i - 9699328u; }
  float4 a = *(const float4*)(src + off);
  float4 b = *(const float4*)(src + off + 4);
  uint4 o;
  o.x = pack_bf16(a.x, a.y); o.y = pack_bf16(a.z, a.w);
  o.z = pack_bf16(b.x, b.y); o.w = pack_bf16(b.z, b.w);
  *(uint4*)(dst + i) = o;
}

// ---------------------------------------------------------------------------
// 128x128-tile GEMM body, C = A * B^T, K=1024, bf16 in, fp32 accumulate.
// global_load_lds staging into UNPADDED stride-32 LDS (lane-contiguous).
// ---------------------------------------------------------------------------
template <bool C_F32>
__device__ __forceinline__ void gemm_body_1024(
    const unsigned short* __restrict__ Arow0,
    const unsigned short* __restrict__ Btile,
    void* __restrict__ Cb, int ldC)
{
  __shared__ unsigned short As[128 * 32];
  __shared__ unsigned short Bs[128 * 32];
  const int tid = threadIdx.x;
  const int lane = tid & 63;
  const int w = tid >> 6;
  const int wr = w >> 1, wc = w & 1;
  const int l15 = lane & 15, quad = lane >> 4;

  const unsigned short* a_src = Arow0 + (size_t)(tid >> 2) * 1024 + (tid & 3) * 8;
  const unsigned short* b_src = Btile + (size_t)(tid >> 2) * 1024 + (tid & 3) * 8;
  unsigned short* a_dst = &As[(tid >> 2) * 32 + (tid & 3) * 8];
  unsigned short* b_dst = &Bs[(tid >> 2) * 32 + (tid & 3) * 8];

  floatx4 zero = {0.f, 0.f, 0.f, 0.f};
  floatx4 acc[4][4];
#pragma unroll
  for (int i = 0; i < 4; i++)
#pragma unroll
    for (int j = 0; j < 4; j++) acc[i][j] = zero;

  for (int k0 = 0; k0 < 1024; k0 += 32) {
    __syncthreads();
    G2L(a_src + k0,         a_dst);
    G2L(a_src + 65536 + k0, a_dst + 2048);   // +64 rows
    G2L(b_src + k0,         b_dst);
    G2L(b_src + 65536 + k0, b_dst + 2048);
    __syncthreads();                          // drains vmcnt incl. lds-DMA
    short8 af[4], bfr[4];
#pragma unroll
    for (int i = 0; i < 4; i++)
      af[i] = *(const short8*)&As[(wr * 64 + i * 16 + l15) * 32 + quad * 8];
#pragma unroll
    for (int j = 0; j < 4; j++)
      bfr[j] = *(const short8*)&Bs[(wc * 64 + j * 16 + l15) * 32 + quad * 8];
#pragma unroll
    for (int i = 0; i < 4; i++)
#pragma unroll
      for (int j = 0; j < 4; j++)
        acc[i][j] = __builtin_amdgcn_mfma_f32_16x16x32_bf16(af[i], bfr[j], acc[i][j], 0, 0, 0);
  }
  // epilogue: C row = quad*4+reg, col = lane&15 (verified m89/m91 layout)
#pragma unroll
  for (int i = 0; i < 4; i++)
#pragma unroll
    for (int j = 0; j < 4; j++)
#pragma unroll
      for (int r = 0; r < 4; r++) {
        size_t off = (size_t)(wr * 64 + i * 16 + quad * 4 + r) * ldC + wc * 64 + j * 16 + l15;
        if (C_F32) ((float*)Cb)[off] = acc[i][j][r];
        else ((unsigned short*)Cb)[off] = f2b(acc[i][j][r]);
      }
}

__global__ __launch_bounds__(256) void gemm_qkv_kernel(
    const unsigned short* __restrict__ x,
    const unsigned short* __restrict__ Wq,
    const unsigned short* __restrict__ Wk,
    const unsigned short* __restrict__ Wv,
    unsigned short* __restrict__ q,
    unsigned short* __restrict__ k,
    unsigned short* __restrict__ v)
{
  const int bx = blockIdx.x, by = blockIdx.y;
  const unsigned short* Btile;
  unsigned short* C;
  int ldC, col0;
  if (by < 8) { Btile = Wq + (size_t)by * 128 * 1024; C = q; ldC = 1024; col0 = by * 128; }
  else if (by == 8) { Btile = Wk; C = k; ldC = 128; col0 = 0; }
  else { Btile = Wv; C = v; ldC = 128; col0 = 0; }
  gemm_body_1024<false>(x + (size_t)bx * 128 * 1024, Btile,
                        C + (size_t)bx * 128 * ldC + col0, ldC);
}

__global__ __launch_bounds__(256) void gemm_out_kernel(
    const unsigned short* __restrict__ ao,
    const unsigned short* __restrict__ Wo,
    float* __restrict__ out)
{
  const int bx = blockIdx.x, by = blockIdx.y;
  gemm_body_1024<true>(ao + (size_t)bx * 128 * 1024, Wo + (size_t)by * 128 * 1024,
                       out + (size_t)bx * 128 * 1024 + by * 128, 1024);
}

// ---------------------------------------------------------------------------
// prep: fused vtrans (blocks 0..255) + vectorized RoPE (8 pairs/thread).
// q gets gain*(1/sqrt(HD))/SOFTCAP folded in.
// ---------------------------------------------------------------------------
__global__ __launch_bounds__(256) void prep_kernel(
    unsigned short* __restrict__ q,
    unsigned short* __restrict__ k,
    const unsigned short* __restrict__ v,
    unsigned short* __restrict__ vT,
    const float* __restrict__ cosT,
    const float* __restrict__ sinT,
    const float* __restrict__ gain)
{
  __shared__ unsigned short tile[32 * 136];
  const int tid = threadIdx.x;
  if (blockIdx.x < 256) {
    const int b = blockIdx.x >> 6, t0 = (blockIdx.x & 63) * 32;
    for (int u = tid; u < 512; u += 256) {
      int r = u >> 4, c = u & 15;
      *(uint4*)&tile[r * 136 + c * 8] =
          *(const uint4*)(v + ((size_t)(b * T_ + t0 + r)) * 128 + c * 8);
    }
    __syncthreads();
    for (int u = tid; u < 512; u += 256) {
      int d = u >> 2, c = u & 3;
      short8 val;
#pragma unroll
      for (int j = 0; j < 8; j++) val[j] = (short)tile[(c * 8 + j) * 136 + d];
      *(short8*)(vT + ((size_t)(b * 128 + d)) * T_ + t0 + c * 8) = val;
    }
    return;
  }
  int idx = (blockIdx.x - 256) * 256 + tid;   // 0 .. 589823
  unsigned short* ptr;
  size_t base;
  int t, j;
  float g;
  if (idx < 524288) {                         // q: (bt, h, dim-octet j)
    j = idx & 7;
    int h = (idx >> 3) & 7;
    int bt = idx >> 6;
    t = bt & (T_ - 1);
    base = (size_t)bt * 1024 + h * 128 + j * 8;
    ptr = q;
    g = gain[h] * 0.0029462782549439484f;     // (1/sqrt(128))/30
  } else {                                    // k
    int id = idx - 524288;
    j = id & 7;
    int bt = id >> 3;
    t = bt & (T_ - 1);
    base = (size_t)bt * 128 + j * 8;
    ptr = k;
    g = 1.f;
  }
  float4 ca = *(const float4*)&cosT[t * 64 + j * 8];
  float4 cb = *(const float4*)&cosT[t * 64 + j * 8 + 4];
  float4 sa = *(const float4*)&sinT[t * 64 + j * 8];
  float4 sb = *(const float4*)&sinT[t * 64 + j * 8 + 4];
  uint4 lo = *(const uint4*)(ptr + base);
  uint4 hi = *(const uint4*)(ptr + base + 64);
  uint4 olo, ohi;
  {
    float a0 = blo(lo.x), a1 = bhi(lo.x), b0 = blo(hi.x), b1 = bhi(hi.x);
    olo.x = pack_bf16((a0 * ca.x - b0 * sa.x) * g, (a1 * ca.y - b1 * sa.y) * g);
    ohi.x = pack_bf16((a0 * sa.x + b0 * ca.x) * g, (a1 * sa.y + b1 * ca.y) * g);
  }
  {
    float a0 = blo(lo.y), a1 = bhi(lo.y), b0 = blo(hi.y), b1 = bhi(hi.y);
    olo.y = pack_bf16((a0 * ca.z - b0 * sa.z) * g, (a1 * ca.w - b1 * sa.w) * g);
    ohi.y = pack_bf16((a0 * sa.z + b0 * ca.z) * g, (a1 * sa.w + b1 * ca.w) * g);
  }
  {
    float a0 = blo(lo.z), a1 = bhi(lo.z), b0 = blo(hi.z), b1 = bhi(hi.z);
    olo.z = pack_bf16((a0 * cb.x - b0 * sb.x) * g, (a1 * cb.y - b1 * sb.y) * g);
    ohi.z = pack_bf16((a0 * sb.x + b0 * cb.x) * g, (a1 * sb.y + b1 * cb.y) * g);
  }
  {
    float a0 = blo(lo.w), a1 = bhi(lo.w), b0 = blo(hi.w), b1 = bhi(hi.w);
    olo.w = pack_bf16((a0 * cb.z - b0 * sb.z) * g, (a1 * cb.w - b1 * sb.w) * g);
    ohi.w = pack_bf16((a0 * sb.z + b0 * cb.z) * g, (a1 * sb.w + b1 * cb.w) * g);
  }
  *(uint4*)(ptr + base) = olo;
  *(uint4*)(ptr + base + 64) = ohi;
}

// ---------------------------------------------------------------------------
// Flash attention. ROUND 10: in-register P redistribution + NSPLIT=4.
// Round-1 counters: Occupancy 18% (2 blocks/CU), MfmaUtil 18%, VALUBusy 39%
// -> TLP-starved latency bound (per-SIMD issue work ~45k cy vs 175k cy dur).
// Fix: (a) eliminate the Pw LDS round-trip. Swapped QK^T leaves lane
// (l15,quad) holding P[key=f*16+quad*4+r][q=g*16+l15]; the PV B-frag needs
// P[key=quad*8+j][q=l15]. pack pairs -> dwords a,b (f=0), c,d (f=1), then
//   permlane32_swap(a,c): a=[a@q0,a@q1,c@q0,c@q1], c=[a@q2,a@q3,c@q2,c@q3]
//   permlane16_swap(a,c): a=[a@q0,a@q2,c@q0,c@q2]=W0(keys 8q+0,1)
//                         c=[a@q1,a@q3,c@q1,c@q3]=W2(keys 8q+4,5)
// (same for b,d -> W1,W3); frag = [W0,W1,W2,W3]. Removes 4 ds_write_b64 +
// 2 ds_read_b128 + lgkmcnt(0) per tile AND frees 10,240B LDS -> 37,376B.
// (b) NSPLIT=4 (grid 1024): 4 blocks/CU now fit in LDS -> 4 waves/SIMD,
// doubling latency hiding. seg=(4qb+4)/4=qb+1 exact.
// ---------------------------------------------------------------------------
template <int NSPLIT>
__global__ __launch_bounds__(256) void attn_kernel(
    const unsigned short* __restrict__ q,
    const unsigned short* __restrict__ k,
    const unsigned short* __restrict__ vT,
    unsigned short* __restrict__ ao,
    unsigned short* __restrict__ Opart,
    float* __restrict__ lbuf)
{
  __shared__ unsigned short Ks[2][16 * 264];   // [buf][dimgroup d][key*8 + j]
  __shared__ unsigned short Vts[2][128 * 40];  // [buf][dim][key]

  const int h = blockIdx.y, b = blockIdx.z;
  const int pr   = blockIdx.x / NSPLIT;
  const int part = blockIdx.x % NSPLIT;
  const int tid = threadIdx.x, lane = tid & 63, w = tid >> 6;
  const int l15 = lane & 15, quad = lane >> 4;

  // K staging: key = tid>>4 (+16), dimgroup = tid&15
  const unsigned short* ksrc =
      k + (size_t)b * T_ * 128 + (size_t)(tid >> 4) * 128 + (tid & 15) * 8;
  const int koff0 = (tid & 15) * 264 + (tid >> 4) * 8;
  const int koff1 = koff0 + 16 * 8;
  // V staging: row = tid>>2 (+64), col8 = tid&3
  const unsigned short* vsrc =
      vT + (size_t)b * 128 * T_ + (size_t)(tid >> 2) * T_ + (tid & 3) * 8;
  const int voff0 = (tid >> 2) * 40 + (tid & 3) * 8;
  const int voff1 = voff0 + 64 * 40;

  const floatx4 zero = {0.f, 0.f, 0.f, 0.f};

  for (int pass = 0; pass < 2; pass++) {
    const int qblock = pass ? (15 - pr) : pr;
    const int qbase = qblock * 128;
    const int qw = qbase + w * 32;            // wave's first q-row
    const int seg = (4 * qblock + 4) / NSPLIT;
    const int ktBeg = part * seg, ktEnd = ktBeg + seg;

    // Q B-frags for 2 q-subtiles x 4 k-chunks
    short8 qf[2][4];
#pragma unroll
    for (int g = 0; g < 2; g++) {
      const unsigned short* qrow =
          q + ((size_t)(b * T_ + qw + g * 16 + l15) * NH_ + h) * HD_;
#pragma unroll
      for (int c = 0; c < 4; c++) qf[g][c] = *(const short8*)(qrow + c * 32 + quad * 8);
    }

    float l_i[2] = {0.f, 0.f};
    floatx4 acc[8][2];
#pragma unroll
    for (int d = 0; d < 8; d++) { acc[d][0] = zero; acc[d][1] = zero; }

    // pass-start barrier: previous pass/prologue reads done before reuse
    __syncthreads();
    // prologue: stage tile ktBeg into buf[ktBeg&1]
    {
      uint4 kr0 = *(const uint4*)(ksrc + (size_t)ktBeg * 4096);
      uint4 kr1 = *(const uint4*)(ksrc + (size_t)ktBeg * 4096 + 2048);
      uint4 vr0 = *(const uint4*)(vsrc + ktBeg * 32);
      uint4 vr1 = *(const uint4*)(vsrc + (size_t)64 * T_ + ktBeg * 32);
      unsigned short* kb = Ks[ktBeg & 1];
      unsigned short* vb = Vts[ktBeg & 1];
      *(uint4*)(kb + koff0) = kr0; *(uint4*)(kb + koff1) = kr1;
      *(uint4*)(vb + voff0) = vr0; *(uint4*)(vb + voff1) = vr1;
    }

    for (int kt = ktBeg; kt < ktEnd; kt++) {
      __syncthreads();                 // publishes buf[kt&1]
      // prefetch tile kt+1 AFTER the barrier (T14): latency hides under
      // compute; write-late store consumes it before the next barrier.
      uint4 kr0, kr1, vr0, vr1;
      const bool more = (kt + 1 < ktEnd);
      if (more) {
        kr0 = *(const uint4*)(ksrc + (size_t)(kt + 1) * 4096);
        kr1 = *(const uint4*)(ksrc + (size_t)(kt + 1) * 4096 + 2048);
        vr0 = *(const uint4*)(vsrc + (kt + 1) * 32);
        vr1 = *(const uint4*)(vsrc + (size_t)64 * T_ + (kt + 1) * 32);
      }

      if (kt * 32 <= qw + 31) {        // wave-uniform causal skip
        const unsigned short* KsC = Ks[kt & 1];
        const unsigned short* VtC = Vts[kt & 1];
        // S^T = K Q^T: 2 key-subtiles (f) x 2 q-subtiles (g), kf reused over g
        floatx4 st[2][2] = {{zero, zero}, {zero, zero}};
#pragma unroll
        for (int c = 0; c < 4; c++) {
          const int dg = (c * 4 + quad) * 264;
          short8 kf0 = *(const short8*)&KsC[dg + l15 * 8];
          short8 kf1 = *(const short8*)&KsC[dg + (16 + l15) * 8];
          st[0][0] = __builtin_amdgcn_mfma_f32_16x16x32_bf16(kf0, qf[0][c], st[0][0], 0, 0, 0);
          st[0][1] = __builtin_amdgcn_mfma_f32_16x16x32_bf16(kf0, qf[1][c], st[0][1], 0, 0, 0);
          st[1][0] = __builtin_amdgcn_mfma_f32_16x16x32_bf16(kf1, qf[0][c], st[1][0], 0, 0, 0);
          st[1][1] = __builtin_amdgcn_mfma_f32_16x16x32_bf16(kf1, qf[1][c], st[1][1], 0, 0, 0);
        }
        // fused softcap+softmax numerator (fixed m=30); P stays in registers,
        // redistributed to PV B-frag layout via permlane swaps (see header).
        float rs[2] = {0.f, 0.f};
        short8 pf0, pf1;
        if (kt * 32 + 31 <= qw) {      // fully unmasked (most iterations)
#pragma unroll
          for (int g = 0; g < 2; g++) {
            float pv[2][4];
#pragma unroll
            for (int f = 0; f < 2; f++)
#pragma unroll
              for (int r = 0; r < 4; r++) {
                float s = st[f][g][r];
                float e = EXP2F(2.8853901f * s);
                float u = RCPF(e + 1.f);
                float p = EXP2F(-86.561707f * u);
                pv[f][r] = p;
                rs[g] += p;
              }
            unsigned int pa = pack_bf16(pv[0][0], pv[0][1]);
            unsigned int pb = pack_bf16(pv[0][2], pv[0][3]);
            unsigned int pc = pack_bf16(pv[1][0], pv[1][1]);
            unsigned int pd = pack_bf16(pv[1][2], pv[1][3]);
            asm("v_permlane32_swap_b32 %0, %1" : "+v"(pa), "+v"(pc));
            asm("v_permlane32_swap_b32 %0, %1" : "+v"(pb), "+v"(pd));
            asm("v_permlane16_swap_b32 %0, %1" : "+v"(pa), "+v"(pc));
            asm("v_permlane16_swap_b32 %0, %1" : "+v"(pb), "+v"(pd));
            uint4 u; u.x = pa; u.y = pb; u.z = pc; u.w = pd;
            (g ? pf1 : pf0) = *(short8*)&u;
          }
        } else {                       // boundary tile: apply causal mask
#pragma unroll
          for (int g = 0; g < 2; g++) {
            float pv[2][4];
            const int qrow = qw + g * 16 + l15;
#pragma unroll
            for (int f = 0; f < 2; f++)
#pragma unroll
              for (int r = 0; r < 4; r++) {
                float s = st[f][g][r];
                float e = EXP2F(2.8853901f * s);
                float u = RCPF(e + 1.f);
                float p = EXP2F(-86.561707f * u);
                int key = kt * 32 + f * 16 + quad * 4 + r;
                p = (key <= qrow) ? p : 0.f;
                pv[f][r] = p;
                rs[g] += p;
              }
            unsigned int pa = pack_bf16(pv[0][0], pv[0][1]);
            unsigned int pb = pack_bf16(pv[0][2], pv[0][3]);
            unsigned int pc = pack_bf16(pv[1][0], pv[1][1]);
            unsigned int pd = pack_bf16(pv[1][2], pv[1][3]);
            asm("v_permlane32_swap_b32 %0, %1" : "+v"(pa), "+v"(pc));
            asm("v_permlane32_swap_b32 %0, %1" : "+v"(pb), "+v"(pd));
            asm("v_permlane16_swap_b32 %0, %1" : "+v"(pa), "+v"(pc));
            asm("v_permlane16_swap_b32 %0, %1" : "+v"(pb), "+v"(pd));
            uint4 u; u.x = pa; u.y = pb; u.z = pc; u.w = pd;
            (g ? pf1 : pf0) = *(short8*)&u;
          }
        }
#pragma unroll
        for (int g = 0; g < 2; g++) {
          float r2 = rs[g] + __shfl_xor(rs[g], 16);
          l_i[g] += r2 + __shfl_xor(r2, 32);
        }
        // O^T += V^T P^T: vf reused over both q-subtiles
#pragma unroll
        for (int d = 0; d < 8; d++) {
          short8 vf = *(const short8*)&VtC[(d * 16 + l15) * 40 + quad * 8];
          acc[d][0] = __builtin_amdgcn_mfma_f32_16x16x32_bf16(vf, pf0, acc[d][0], 0, 0, 0);
          acc[d][1] = __builtin_amdgcn_mfma_f32_16x16x32_bf16(vf, pf1, acc[d][1], 0, 0, 0);
        }
      }

      if (more) {                      // write-late: stage kt+1 after compute
        unsigned short* kb = Ks[(kt + 1) & 1];
        unsigned short* vb = Vts[(kt + 1) & 1];
        *(uint4*)(kb + koff0) = kr0; *(uint4*)(kb + koff1) = kr1;
        *(uint4*)(vb + voff0) = vr0; *(uint4*)(vb + voff1) = vr1;
      }
    }

    // epilogue: O^T D-layout col=l15=q, row=quad*4+r = dim within d-tile
#pragma unroll
    for (int g = 0; g < 2; g++) {
      const size_t rowidx = (size_t)(b * T_ + qw + g * 16 + l15) * NH_ + h;
      if (NSPLIT == 1) {
        float linv = 1.f / l_i[g];
        unsigned short* aop = ao + rowidx * HD_ + quad * 4;
#pragma unroll
        for (int d = 0; d < 8; d++) {
          uint2 o;
          o.x = pack_bf16(acc[d][g][0] * linv, acc[d][g][1] * linv);
          o.y = pack_bf16(acc[d][g][2] * linv, acc[d][g][3] * linv);
          *(uint2*)(aop + d * 16) = o;
        }
      } else {
        unsigned short* dst =
            ((part == NSPLIT - 1) ? ao : Opart + (size_t)part * 8388608u) +
            rowidx * HD_ + quad * 4;
#pragma unroll
        for (int d = 0; d < 8; d++) {
          uint2 o;
          o.x = pack_bf16(acc[d][g][0], acc[d][g][1]);
          o.y = pack_bf16(acc[d][g][2], acc[d][g][3]);
          *(uint2*)(dst + d * 16) = o;
        }
        if (quad == 0) lbuf[(size_t)part * 65536u + rowidx] = l_i[g];
      }
    }
  }
}

// ao = (sum of partials + ao) / (sum of l), 8 bf16 elems per thread
template <int NSPLIT>
__global__ __launch_bounds__(256) void combine_kernel(
    const unsigned short* __restrict__ Opart,
    const float* __restrict__ lbuf,
    unsigned short* __restrict__ ao)
{
  size_t i = ((size_t)blockIdx.x * 256 + threadIdx.x) * 8;
  size_t r = i >> 7;                          // (b*T+t)*NH+h
  float ls = 0.f;
#pragma unroll
  for (int p = 0; p < NSPLIT; p++) ls += lbuf[(size_t)p * 65536u + r];
  float linv = RCPF(ls);
  uint4 c = *(const uint4*)(ao + i);
  float v0 = blo(c.x), v1 = bhi(c.x), v2 = blo(c.y), v3 = bhi(c.y);
  float v4 = blo(c.z), v5 = bhi(c.z), v6 = blo(c.w), v7 = bhi(c.w);
#pragma unroll
  for (int p = 0; p < NSPLIT - 1; p++) {
    uint4 a = *(const uint4*)(Opart + (size_t)p * 8388608u + i);
    v0 += blo(a.x); v1 += bhi(a.x); v2 += blo(a.y); v3 += bhi(a.y);
    v4 += blo(a.z); v5 += bhi(a.z); v6 += blo(a.w); v7 += bhi(a.w);
  }
  uint4 o;
  o.x = pack_bf16(v0 * linv, v1 * linv);
  o.y = pack_bf16(v2 * linv, v3 * linv);
  o.z = pack_bf16(v4 * linv, v5 * linv);
  o.w = pack_bf16(v6 * linv, v7 * linv);
  *(uint4*)(ao + i) = o;
}

extern "C" void kernel_launch(void* const* d_in, const int* in_sizes, int n_in,
                              void* d_out, int out_size, void* d_ws, size_t ws_size,
                              hipStream_t stream) {
  const float* x    = (const float*)d_in[0];
  const float* Wq   = (const float*)d_in[1];
  const float* Wk   = (const float*)d_in[2];
  const float* Wv   = (const float*)d_in[3];
  const float* Wo   = (const float*)d_in[4];
  const float* gain = (const float*)d_in[5];
  const float* cosT = (const float*)d_in[6];
  const float* sinT = (const float*)d_in[7];
  float* out = (float*)d_out;

  unsigned short* ws = (unsigned short*)d_ws;  // elem offsets (bf16)
  unsigned short* blob = ws;                   // x|Wq|Wk|Wv|Wo bf16
  unsigned short* xb  = blob;
  unsigned short* Wqb = blob + 8388608u;
  unsigned short* Wkb = blob + 9437184u;
  unsigned short* Wvb = blob + 9568256u;
  unsigned short* Wob = blob + 9699328u;
  unsigned short* q   = ws + 10747904u;        // 8388608 elems
  unsigned short* kk  = ws + 19136512u;        // 1048576
  unsigned short* v   = ws + 20185088u;        // 1048576
  unsigned short* vT  = ws + 21233664u;        // 1048576
  unsigned short* ao  = xb;                    // alias: xb dead after gemm_qkv
  unsigned short* Opart = ws + 22282240u;      // up to 3 x 8388608 elems
  float* l2 = (float*)((char*)d_ws + 61341696u);   // 2 x 65536 f32
  const size_t need2 = 61865984ull;
  float* l4 = (float*)((char*)d_ws + 94896128u);   // 4 x 65536 f32
  const size_t need4 = 95944704ull;

  // 0. f32 -> bf16 convert of all GEMM operands
  cvt_kernel<<<5248, 256, 0, stream>>>(x, Wq, Wk, Wv, Wo, blob);
  // 1. fused QKV projection (M=8192, K=1024, N=1024+128+128)
  gemm_qkv_kernel<<<dim3(64, 10), 256, 0, stream>>>(xb, Wqb, Wkb, Wvb, q, kk, v);
  // 2. prep: vtrans (256 blocks) + vectorized RoPE (2304 blocks)
  prep_kernel<<<2560, 256, 0, stream>>>(q, kk, v, vT, cosT, sinT, gain);
  // 3. flash attention + combine (4-way key split when workspace allows:
  //    1024 blocks = 4 blocks/CU, enabled by the 37,376B LDS footprint)
  if (ws_size >= need4) {
    attn_kernel<4><<<dim3(32, 8, 4), 256, 0, stream>>>(q, kk, vT, ao, Opart, l4);
    combine_kernel<4><<<4096, 256, 0, stream>>>(Opart, l4, ao);
  } else if (ws_size >= need2) {
    attn_kernel<2><<<dim3(16, 8, 4), 256, 0, stream>>>(q, kk, vT, ao, Opart, l2);
    combine_kernel<2><<<4096, 256, 0, stream>>>(Opart, l2, ao);
  } else {
    attn_kernel<1><<<dim3(8, 8, 4), 256, 0, stream>>>(q, kk, vT, ao, Opart, l2);
  }
  // 4. output projection (bf16 -> f32 out)
  gemm_out_kernel<<<dim3(64, 8), 256, 0, stream>>>(ao, Wob, out);
}

// Round 3
// 234.285 us; speedup vs baseline: 1.0561x; 1.0561x over previous
//
#include <hip/hip_runtime.h>
#include <hip/hip_bf16.h>

// Problem constants (B=4, T=2048, D=1024, NH=8, NKV=1, HD=128)
#define B_ 4
#define T_ 2048
#define D_ 1024
#define NH_ 8
#define HD_ 128

typedef short short8 __attribute__((ext_vector_type(8)));   // 8 bf16 (4 VGPRs) MFMA frag
typedef float floatx4 __attribute__((ext_vector_type(4)));  // MFMA accumulator

#if __has_builtin(__builtin_amdgcn_exp2f)
#define EXP2F __builtin_amdgcn_exp2f
#else
#define EXP2F exp2f
#endif
#if __has_builtin(__builtin_amdgcn_rcpf)
#define RCPF __builtin_amdgcn_rcpf
#else
__device__ __forceinline__ float RCPF(float x) { return 1.f / x; }
#endif

// async global->LDS 16B copy (m97 lever); LDS dest must be wave-uniform base
// + lane*16B, which the GEMM staging pattern satisfies by construction.
#if __has_builtin(__builtin_amdgcn_global_load_lds)
#define G2L(gp, lp)                                                        \
  __builtin_amdgcn_global_load_lds(                                        \
      (const __attribute__((address_space(1))) unsigned int*)(gp),         \
      (__attribute__((address_space(3))) unsigned int*)(lp), 16, 0, 0)
#else
#define G2L(gp, lp) (*(uint4*)(lp) = *(const uint4*)(gp))
#endif

__device__ __forceinline__ unsigned short f2b(float f) {
  union { float fl; unsigned int i; } v; v.fl = f;
  unsigned int r = v.i + 0x7fffu + ((v.i >> 16) & 1u);  // RNE, non-NaN inputs
  return (unsigned short)(r >> 16);
}
// pack two f32 -> two bf16 (round-to-nearest): low16 = a, high16 = b
__device__ __forceinline__ unsigned int pack_bf16(float a, float b) {
  unsigned int ua = __float_as_uint(a) + 0x8000u;
  unsigned int ub = __float_as_uint(b) + 0x8000u;
  return (ua >> 16) | (ub & 0xffff0000u);
}
__device__ __forceinline__ float blo(unsigned int u) { return __uint_as_float(u << 16); }
__device__ __forceinline__ float bhi(unsigned int u) { return __uint_as_float(u & 0xffff0000u); }

// ---------------------------------------------------------------------------
// One-shot f32 -> bf16 convert of x|Wq|Wk|Wv|Wo into a contiguous bf16 blob.
// ---------------------------------------------------------------------------
__global__ __launch_bounds__(256) void cvt_kernel(
    const float* __restrict__ x,  const float* __restrict__ wq,
    const float* __restrict__ wk, const float* __restrict__ wv,
    const float* __restrict__ wo, unsigned short* __restrict__ dst)
{
  size_t i = ((size_t)blockIdx.x * 256 + threadIdx.x) * 8;
  const float* src; size_t off;
  if      (i <  8388608u) { src = x;  off = i; }
  else if (i <  9437184u) { src = wq; off = i - 8388608u; }
  else if (i <  9568256u) { src = wk; off = i - 9437184u; }
  else if (i <  9699328u) { src = wv; off = i - 9568256u; }
  else                    { src = wo; off = i - 9699328u; }
  float4 a = *(const float4*)(src + off);
  float4 b = *(const float4*)(src + off + 4);
  uint4 o;
  o.x = pack_bf16(a.x, a.y); o.y = pack_bf16(a.z, a.w);
  o.z = pack_bf16(b.x, b.y); o.w = pack_bf16(b.z, b.w);
  *(uint4*)(dst + i) = o;
}

// ---------------------------------------------------------------------------
// 128x128-tile GEMM body, C = A * B^T, K=1024, bf16 in, fp32 accumulate.
// global_load_lds staging into UNPADDED stride-32 LDS (lane-contiguous).
// ---------------------------------------------------------------------------
template <bool C_F32>
__device__ __forceinline__ void gemm_body_1024(
    const unsigned short* __restrict__ Arow0,
    const unsigned short* __restrict__ Btile,
    void* __restrict__ Cb, int ldC)
{
  __shared__ unsigned short As[128 * 32];
  __shared__ unsigned short Bs[128 * 32];
  const int tid = threadIdx.x;
  const int lane = tid & 63;
  const int w = tid >> 6;
  const int wr = w >> 1, wc = w & 1;
  const int l15 = lane & 15, quad = lane >> 4;

  const unsigned short* a_src = Arow0 + (size_t)(tid >> 2) * 1024 + (tid & 3) * 8;
  const unsigned short* b_src = Btile + (size_t)(tid >> 2) * 1024 + (tid & 3) * 8;
  unsigned short* a_dst = &As[(tid >> 2) * 32 + (tid & 3) * 8];
  unsigned short* b_dst = &Bs[(tid >> 2) * 32 + (tid & 3) * 8];

  floatx4 zero = {0.f, 0.f, 0.f, 0.f};
  floatx4 acc[4][4];
#pragma unroll
  for (int i = 0; i < 4; i++)
#pragma unroll
    for (int j = 0; j < 4; j++) acc[i][j] = zero;

  for (int k0 = 0; k0 < 1024; k0 += 32) {
    __syncthreads();
    G2L(a_src + k0,         a_dst);
    G2L(a_src + 65536 + k0, a_dst + 2048);   // +64 rows
    G2L(b_src + k0,         b_dst);
    G2L(b_src + 65536 + k0, b_dst + 2048);
    __syncthreads();                          // drains vmcnt incl. lds-DMA
    short8 af[4], bfr[4];
#pragma unroll
    for (int i = 0; i < 4; i++)
      af[i] = *(const short8*)&As[(wr * 64 + i * 16 + l15) * 32 + quad * 8];
#pragma unroll
    for (int j = 0; j < 4; j++)
      bfr[j] = *(const short8*)&Bs[(wc * 64 + j * 16 + l15) * 32 + quad * 8];
#pragma unroll
    for (int i = 0; i < 4; i++)
#pragma unroll
      for (int j = 0; j < 4; j++)
        acc[i][j] = __builtin_amdgcn_mfma_f32_16x16x32_bf16(af[i], bfr[j], acc[i][j], 0, 0, 0);
  }
  // epilogue: C row = quad*4+reg, col = lane&15 (verified m89/m91 layout)
#pragma unroll
  for (int i = 0; i < 4; i++)
#pragma unroll
    for (int j = 0; j < 4; j++)
#pragma unroll
      for (int r = 0; r < 4; r++) {
        size_t off = (size_t)(wr * 64 + i * 16 + quad * 4 + r) * ldC + wc * 64 + j * 16 + l15;
        if (C_F32) ((float*)Cb)[off] = acc[i][j][r];
        else ((unsigned short*)Cb)[off] = f2b(acc[i][j][r]);
      }
}

__global__ __launch_bounds__(256) void gemm_qkv_kernel(
    const unsigned short* __restrict__ x,
    const unsigned short* __restrict__ Wq,
    const unsigned short* __restrict__ Wk,
    const unsigned short* __restrict__ Wv,
    unsigned short* __restrict__ q,
    unsigned short* __restrict__ k,
    unsigned short* __restrict__ v)
{
  const int bx = blockIdx.x, by = blockIdx.y;
  const unsigned short* Btile;
  unsigned short* C;
  int ldC, col0;
  if (by < 8) { Btile = Wq + (size_t)by * 128 * 1024; C = q; ldC = 1024; col0 = by * 128; }
  else if (by == 8) { Btile = Wk; C = k; ldC = 128; col0 = 0; }
  else { Btile = Wv; C = v; ldC = 128; col0 = 0; }
  gemm_body_1024<false>(x + (size_t)bx * 128 * 1024, Btile,
                        C + (size_t)bx * 128 * ldC + col0, ldC);
}

__global__ __launch_bounds__(256) void gemm_out_kernel(
    const unsigned short* __restrict__ ao,
    const unsigned short* __restrict__ Wo,
    float* __restrict__ out)
{
  const int bx = blockIdx.x, by = blockIdx.y;
  gemm_body_1024<true>(ao + (size_t)bx * 128 * 1024, Wo + (size_t)by * 128 * 1024,
                       out + (size_t)bx * 128 * 1024 + by * 128, 1024);
}

// ---------------------------------------------------------------------------
// prep: fused vtrans (blocks 0..255) + vectorized RoPE (8 pairs/thread).
// q gets gain*(1/sqrt(HD))/SOFTCAP folded in.
// ---------------------------------------------------------------------------
__global__ __launch_bounds__(256) void prep_kernel(
    unsigned short* __restrict__ q,
    unsigned short* __restrict__ k,
    const unsigned short* __restrict__ v,
    unsigned short* __restrict__ vT,
    const float* __restrict__ cosT,
    const float* __restrict__ sinT,
    const float* __restrict__ gain)
{
  __shared__ unsigned short tile[32 * 136];
  const int tid = threadIdx.x;
  if (blockIdx.x < 256) {
    const int b = blockIdx.x >> 6, t0 = (blockIdx.x & 63) * 32;
    for (int u = tid; u < 512; u += 256) {
      int r = u >> 4, c = u & 15;
      *(uint4*)&tile[r * 136 + c * 8] =
          *(const uint4*)(v + ((size_t)(b * T_ + t0 + r)) * 128 + c * 8);
    }
    __syncthreads();
    for (int u = tid; u < 512; u += 256) {
      int d = u >> 2, c = u & 3;
      short8 val;
#pragma unroll
      for (int j = 0; j < 8; j++) val[j] = (short)tile[(c * 8 + j) * 136 + d];
      *(short8*)(vT + ((size_t)(b * 128 + d)) * T_ + t0 + c * 8) = val;
    }
    return;
  }
  int idx = (blockIdx.x - 256) * 256 + tid;   // 0 .. 589823
  unsigned short* ptr;
  size_t base;
  int t, j;
  float g;
  if (idx < 524288) {                         // q: (bt, h, dim-octet j)
    j = idx & 7;
    int h = (idx >> 3) & 7;
    int bt = idx >> 6;
    t = bt & (T_ - 1);
    base = (size_t)bt * 1024 + h * 128 + j * 8;
    ptr = q;
    g = gain[h] * 0.0029462782549439484f;     // (1/sqrt(128))/30
  } else {                                    // k
    int id = idx - 524288;
    j = id & 7;
    int bt = id >> 3;
    t = bt & (T_ - 1);
    base = (size_t)bt * 128 + j * 8;
    ptr = k;
    g = 1.f;
  }
  float4 ca = *(const float4*)&cosT[t * 64 + j * 8];
  float4 cb = *(const float4*)&cosT[t * 64 + j * 8 + 4];
  float4 sa = *(const float4*)&sinT[t * 64 + j * 8];
  float4 sb = *(const float4*)&sinT[t * 64 + j * 8 + 4];
  uint4 lo = *(const uint4*)(ptr + base);
  uint4 hi = *(const uint4*)(ptr + base + 64);
  uint4 olo, ohi;
  {
    float a0 = blo(lo.x), a1 = bhi(lo.x), b0 = blo(hi.x), b1 = bhi(hi.x);
    olo.x = pack_bf16((a0 * ca.x - b0 * sa.x) * g, (a1 * ca.y - b1 * sa.y) * g);
    ohi.x = pack_bf16((a0 * sa.x + b0 * ca.x) * g, (a1 * sa.y + b1 * ca.y) * g);
  }
  {
    float a0 = blo(lo.y), a1 = bhi(lo.y), b0 = blo(hi.y), b1 = bhi(hi.y);
    olo.y = pack_bf16((a0 * ca.z - b0 * sa.z) * g, (a1 * ca.w - b1 * sa.w) * g);
    ohi.y = pack_bf16((a0 * sa.z + b0 * ca.z) * g, (a1 * sa.w + b1 * ca.w) * g);
  }
  {
    float a0 = blo(lo.z), a1 = bhi(lo.z), b0 = blo(hi.z), b1 = bhi(hi.z);
    olo.z = pack_bf16((a0 * cb.x - b0 * sb.x) * g, (a1 * cb.y - b1 * sb.y) * g);
    ohi.z = pack_bf16((a0 * sb.x + b0 * cb.x) * g, (a1 * sb.y + b1 * cb.y) * g);
  }
  {
    float a0 = blo(lo.w), a1 = bhi(lo.w), b0 = blo(hi.w), b1 = bhi(hi.w);
    olo.w = pack_bf16((a0 * cb.z - b0 * sb.z) * g, (a1 * cb.w - b1 * sb.w) * g);
    ohi.w = pack_bf16((a0 * sb.z + b0 * cb.z) * g, (a1 * sb.w + b1 * cb.w) * g);
  }
  *(uint4*)(ptr + base) = olo;
  *(uint4*)(ptr + base + 64) = ohi;
}

// ---------------------------------------------------------------------------
// Flash attention. ROUND 11: break the 128-register occupancy cliff.
// Rounds 0-2 all showed Occupancy pinned at 18% regardless of LDS/grid: the
// cap was registers. VGPR_Count=104 EXCLUDES the 64-AGPR accumulator
// (acc[8][2]); 168 total regs/wave > 128 -> only 2 waves/SIMD (m69: wave
// slots halve at 64/128/256). Fix: halve per-wave q-tile to 16 rows (drop
// the g dimension): acc 64->32, qf 32->16, st 16->8 => ~100-110 total regs
// < 128 -> 4 waves/SIMD, enforced via __launch_bounds__(256, 4).
// Block = 4 waves x 16 rows = 64 q-rows; 32 chunks/(b,h), paired
// (qc, 31-qc) -> uniform 33 k-tiles per block at NSPLIT=2 (seg=chunk+1
// exact). Grid dim3(32,8,4)=1024 blocks = 4 blocks/CU (LDS 4x37376 fits).
// NSPLIT=2 keeps Q-refetch / partial-write traffic at round-1 levels
// (round-2's NSPLIT=4 traffic tax is reverted).
// In-register P redistribution (permlane32+16 swaps) retained from round 10.
// T14 issue-early/write-late K/V staging retained from round 9.
// ---------------------------------------------------------------------------
template <int NSPLIT>
__global__ __launch_bounds__(256, 4) void attn_kernel(
    const unsigned short* __restrict__ q,
    const unsigned short* __restrict__ k,
    const unsigned short* __restrict__ vT,
    unsigned short* __restrict__ ao,
    unsigned short* __restrict__ Opart,
    float* __restrict__ lbuf)
{
  __shared__ unsigned short Ks[2][16 * 264];   // [buf][dimgroup d][key*8 + j]
  __shared__ unsigned short Vts[2][128 * 40];  // [buf][dim][key]

  const int h = blockIdx.y, b = blockIdx.z;
  const int pr   = blockIdx.x / NSPLIT;        // 0..15 (chunk-pair index)
  const int part = blockIdx.x % NSPLIT;
  const int tid = threadIdx.x, lane = tid & 63, w = tid >> 6;
  const int l15 = lane & 15, quad = lane >> 4;

  // K staging: key = tid>>4 (+16), dimgroup = tid&15
  const unsigned short* ksrc =
      k + (size_t)b * T_ * 128 + (size_t)(tid >> 4) * 128 + (tid & 15) * 8;
  const int koff0 = (tid & 15) * 264 + (tid >> 4) * 8;
  const int koff1 = koff0 + 16 * 8;
  // V staging: row = tid>>2 (+64), col8 = tid&3
  const unsigned short* vsrc =
      vT + (size_t)b * 128 * T_ + (size_t)(tid >> 2) * T_ + (tid & 3) * 8;
  const int voff0 = (tid >> 2) * 40 + (tid & 3) * 8;
  const int voff1 = voff0 + 64 * 40;

  const floatx4 zero = {0.f, 0.f, 0.f, 0.f};

  for (int pass = 0; pass < 2; pass++) {
    const int chunk = pass ? (31 - pr) : pr;   // 64-row q-chunk index
    const int qw = chunk * 64 + w * 16;        // wave's first q-row
    const int seg = (2 * chunk + 2) / NSPLIT;  // exact for NSPLIT in {1,2}
    const int ktBeg = part * seg, ktEnd = ktBeg + seg;

    // Q B-frags: 1 q-subtile x 4 k-chunks
    short8 qf[4];
    {
      const unsigned short* qrow =
          q + ((size_t)(b * T_ + qw + l15) * NH_ + h) * HD_;
#pragma unroll
      for (int c = 0; c < 4; c++) qf[c] = *(const short8*)(qrow + c * 32 + quad * 8);
    }

    float l_i = 0.f;
    floatx4 acc[8];
#pragma unroll
    for (int d = 0; d < 8; d++) acc[d] = zero;

    // pass-start barrier: previous pass/prologue reads done before reuse
    __syncthreads();
    // prologue: stage tile ktBeg into buf[ktBeg&1]
    {
      uint4 kr0 = *(const uint4*)(ksrc + (size_t)ktBeg * 4096);
      uint4 kr1 = *(const uint4*)(ksrc + (size_t)ktBeg * 4096 + 2048);
      uint4 vr0 = *(const uint4*)(vsrc + ktBeg * 32);
      uint4 vr1 = *(const uint4*)(vsrc + (size_t)64 * T_ + ktBeg * 32);
      unsigned short* kb = Ks[ktBeg & 1];
      unsigned short* vb = Vts[ktBeg & 1];
      *(uint4*)(kb + koff0) = kr0; *(uint4*)(kb + koff1) = kr1;
      *(uint4*)(vb + voff0) = vr0; *(uint4*)(vb + voff1) = vr1;
    }

    for (int kt = ktBeg; kt < ktEnd; kt++) {
      __syncthreads();                 // publishes buf[kt&1]
      // prefetch tile kt+1 AFTER the barrier (T14): latency hides under
      // compute; write-late store consumes it before the next barrier.
      uint4 kr0, kr1, vr0, vr1;
      const bool more = (kt + 1 < ktEnd);
      if (more) {
        kr0 = *(const uint4*)(ksrc + (size_t)(kt + 1) * 4096);
        kr1 = *(const uint4*)(ksrc + (size_t)(kt + 1) * 4096 + 2048);
        vr0 = *(const uint4*)(vsrc + (kt + 1) * 32);
        vr1 = *(const uint4*)(vsrc + (size_t)64 * T_ + (kt + 1) * 32);
      }

      if (kt * 32 <= qw + 15) {        // wave-uniform causal skip
        const unsigned short* KsC = Ks[kt & 1];
        const unsigned short* VtC = Vts[kt & 1];
        // S^T = K Q^T: 2 key-subtiles (f), 1 q-subtile
        floatx4 st[2] = {zero, zero};
#pragma unroll
        for (int c = 0; c < 4; c++) {
          const int dg = (c * 4 + quad) * 264;
          short8 kf0 = *(const short8*)&KsC[dg + l15 * 8];
          short8 kf1 = *(const short8*)&KsC[dg + (16 + l15) * 8];
          st[0] = __builtin_amdgcn_mfma_f32_16x16x32_bf16(kf0, qf[c], st[0], 0, 0, 0);
          st[1] = __builtin_amdgcn_mfma_f32_16x16x32_bf16(kf1, qf[c], st[1], 0, 0, 0);
        }
        // fused softcap+softmax numerator (fixed m=30); P stays in registers,
        // redistributed to the PV B-frag layout via permlane swaps:
        // lane(l15,quad) holds P[key=f*16+quad*4+r][q=l15]; target frag wants
        // keys quad*8+j. pack pairs->dwords a,b (f=0), c,d (f=1);
        // permlane32_swap + permlane16_swap yield [W0,W1,W2,W3] (verified
        // numerically in rounds 10-11).
        float rs = 0.f;
        short8 pf;
        {
          float pv[2][4];
          if (kt * 32 + 31 <= qw) {    // fully unmasked (most iterations)
#pragma unroll
            for (int f = 0; f < 2; f++)
#pragma unroll
              for (int r = 0; r < 4; r++) {
                float s = st[f][r];
                float e = EXP2F(2.8853901f * s);
                float u = RCPF(e + 1.f);
                float p = EXP2F(-86.561707f * u);
                pv[f][r] = p;
                rs += p;
              }
          } else {                     // boundary tile: apply causal mask
            const int qrow = qw + l15;
#pragma unroll
            for (int f = 0; f < 2; f++)
#pragma unroll
              for (int r = 0; r < 4; r++) {
                float s = st[f][r];
                float e = EXP2F(2.8853901f * s);
                float u = RCPF(e + 1.f);
                float p = EXP2F(-86.561707f * u);
                int key = kt * 32 + f * 16 + quad * 4 + r;
                p = (key <= qrow) ? p : 0.f;
                pv[f][r] = p;
                rs += p;
              }
          }
          unsigned int pa = pack_bf16(pv[0][0], pv[0][1]);
          unsigned int pb = pack_bf16(pv[0][2], pv[0][3]);
          unsigned int pc = pack_bf16(pv[1][0], pv[1][1]);
          unsigned int pd = pack_bf16(pv[1][2], pv[1][3]);
          asm("v_permlane32_swap_b32 %0, %1" : "+v"(pa), "+v"(pc));
          asm("v_permlane32_swap_b32 %0, %1" : "+v"(pb), "+v"(pd));
          asm("v_permlane16_swap_b32 %0, %1" : "+v"(pa), "+v"(pc));
          asm("v_permlane16_swap_b32 %0, %1" : "+v"(pb), "+v"(pd));
          uint4 u; u.x = pa; u.y = pb; u.z = pc; u.w = pd;
          pf = *(short8*)&u;
        }
        {
          float r2 = rs + __shfl_xor(rs, 16);
          l_i += r2 + __shfl_xor(r2, 32);
        }
        // O^T += V^T P^T
#pragma unroll
        for (int d = 0; d < 8; d++) {
          short8 vf = *(const short8*)&VtC[(d * 16 + l15) * 40 + quad * 8];
          acc[d] = __builtin_amdgcn_mfma_f32_16x16x32_bf16(vf, pf, acc[d], 0, 0, 0);
        }
      }

      if (more) {                      // write-late: stage kt+1 after compute
        unsigned short* kb = Ks[(kt + 1) & 1];
        unsigned short* vb = Vts[(kt + 1) & 1];
        *(uint4*)(kb + koff0) = kr0; *(uint4*)(kb + koff1) = kr1;
        *(uint4*)(vb + voff0) = vr0; *(uint4*)(vb + voff1) = vr1;
      }
    }

    // epilogue: O^T D-layout col=l15=q, row=quad*4+r = dim within d-tile
    {
      const size_t rowidx = (size_t)(b * T_ + qw + l15) * NH_ + h;
      if (NSPLIT == 1) {
        float linv = 1.f / l_i;
        unsigned short* aop = ao + rowidx * HD_ + quad * 4;
#pragma unroll
        for (int d = 0; d < 8; d++) {
          uint2 o;
          o.x = pack_bf16(acc[d][0] * linv, acc[d][1] * linv);
          o.y = pack_bf16(acc[d][2] * linv, acc[d][3] * linv);
          *(uint2*)(aop + d * 16) = o;
        }
      } else {
        unsigned short* dst =
            ((part == NSPLIT - 1) ? ao : Opart + (size_t)part * 8388608u) +
            rowidx * HD_ + quad * 4;
#pragma unroll
        for (int d = 0; d < 8; d++) {
          uint2 o;
          o.x = pack_bf16(acc[d][0], acc[d][1]);
          o.y = pack_bf16(acc[d][2], acc[d][3]);
          *(uint2*)(dst + d * 16) = o;
        }
        if (quad == 0) lbuf[(size_t)part * 65536u + rowidx] = l_i;
      }
    }
  }
}

// ao = (sum of partials + ao) / (sum of l), 8 bf16 elems per thread
template <int NSPLIT>
__global__ __launch_bounds__(256) void combine_kernel(
    const unsigned short* __restrict__ Opart,
    const float* __restrict__ lbuf,
    unsigned short* __restrict__ ao)
{
  size_t i = ((size_t)blockIdx.x * 256 + threadIdx.x) * 8;
  size_t r = i >> 7;                          // (b*T+t)*NH+h
  float ls = 0.f;
#pragma unroll
  for (int p = 0; p < NSPLIT; p++) ls += lbuf[(size_t)p * 65536u + r];
  float linv = RCPF(ls);
  uint4 c = *(const uint4*)(ao + i);
  float v0 = blo(c.x), v1 = bhi(c.x), v2 = blo(c.y), v3 = bhi(c.y);
  float v4 = blo(c.z), v5 = bhi(c.z), v6 = blo(c.w), v7 = bhi(c.w);
#pragma unroll
  for (int p = 0; p < NSPLIT - 1; p++) {
    uint4 a = *(const uint4*)(Opart + (size_t)p * 8388608u + i);
    v0 += blo(a.x); v1 += bhi(a.x); v2 += blo(a.y); v3 += bhi(a.y);
    v4 += blo(a.z); v5 += bhi(a.z); v6 += blo(a.w); v7 += bhi(a.w);
  }
  uint4 o;
  o.x = pack_bf16(v0 * linv, v1 * linv);
  o.y = pack_bf16(v2 * linv, v3 * linv);
  o.z = pack_bf16(v4 * linv, v5 * linv);
  o.w = pack_bf16(v6 * linv, v7 * linv);
  *(uint4*)(ao + i) = o;
}

extern "C" void kernel_launch(void* const* d_in, const int* in_sizes, int n_in,
                              void* d_out, int out_size, void* d_ws, size_t ws_size,
                              hipStream_t stream) {
  const float* x    = (const float*)d_in[0];
  const float* Wq   = (const float*)d_in[1];
  const float* Wk   = (const float*)d_in[2];
  const float* Wv   = (const float*)d_in[3];
  const float* Wo   = (const float*)d_in[4];
  const float* gain = (const float*)d_in[5];
  const float* cosT = (const float*)d_in[6];
  const float* sinT = (const float*)d_in[7];
  float* out = (float*)d_out;

  unsigned short* ws = (unsigned short*)d_ws;  // elem offsets (bf16)
  unsigned short* blob = ws;                   // x|Wq|Wk|Wv|Wo bf16
  unsigned short* xb  = blob;
  unsigned short* Wqb = blob + 8388608u;
  unsigned short* Wkb = blob + 9437184u;
  unsigned short* Wvb = blob + 9568256u;
  unsigned short* Wob = blob + 9699328u;
  unsigned short* q   = ws + 10747904u;        // 8388608 elems
  unsigned short* kk  = ws + 19136512u;        // 1048576
  unsigned short* v   = ws + 20185088u;        // 1048576
  unsigned short* vT  = ws + 21233664u;        // 1048576
  unsigned short* ao  = xb;                    // alias: xb dead after gemm_qkv
  unsigned short* Opart = ws + 22282240u;      // 8388608 elems (2-way partial)
  float* l2 = (float*)((char*)d_ws + 61341696u);   // 2 x 65536 f32
  const size_t need2 = 61865984ull;

  // 0. f32 -> bf16 convert of all GEMM operands
  cvt_kernel<<<5248, 256, 0, stream>>>(x, Wq, Wk, Wv, Wo, blob);
  // 1. fused QKV projection (M=8192, K=1024, N=1024+128+128)
  gemm_qkv_kernel<<<dim3(64, 10), 256, 0, stream>>>(xb, Wqb, Wkb, Wvb, q, kk, v);
  // 2. prep: vtrans (256 blocks) + vectorized RoPE (2304 blocks)
  prep_kernel<<<2560, 256, 0, stream>>>(q, kk, v, vT, cosT, sinT, gain);
  // 3. flash attention + combine. 64-row blocks, 16 chunk-pairs x NSPLIT=2:
  //    grid 1024 = 4 blocks/CU; <=128 regs/wave -> 4 waves/SIMD.
  if (ws_size >= need2) {
    attn_kernel<2><<<dim3(32, 8, 4), 256, 0, stream>>>(q, kk, vT, ao, Opart, l2);
    combine_kernel<2><<<4096, 256, 0, stream>>>(Opart, l2, ao);
  } else {
    attn_kernel<1><<<dim3(16, 8, 4), 256, 0, stream>>>(q, kk, vT, ao, Opart, l2);
  }
  // 4. output projection (bf16 -> f32 out)
  gemm_out_kernel<<<dim3(64, 8), 256, 0, stream>>>(ao, Wob, out);
}

// Round 4
// 234.028 us; speedup vs baseline: 1.0573x; 1.0011x over previous
//
#include <hip/hip_runtime.h>
#include <hip/hip_bf16.h>

// Problem constants (B=4, T=2048, D=1024, NH=8, NKV=1, HD=128)
#define B_ 4
#define T_ 2048
#define D_ 1024
#define NH_ 8
#define HD_ 128

typedef short short8 __attribute__((ext_vector_type(8)));    // 8 bf16 (4 VGPRs) MFMA frag
typedef float floatx4 __attribute__((ext_vector_type(4)));   // 16x16 MFMA accumulator
typedef float floatx16 __attribute__((ext_vector_type(16))); // 32x32 MFMA accumulator

#if __has_builtin(__builtin_amdgcn_exp2f)
#define EXP2F __builtin_amdgcn_exp2f
#else
#define EXP2F exp2f
#endif
#if __has_builtin(__builtin_amdgcn_rcpf)
#define RCPF __builtin_amdgcn_rcpf
#else
__device__ __forceinline__ float RCPF(float x) { return 1.f / x; }
#endif

// async global->LDS 16B copy (m97 lever); LDS dest must be wave-uniform base
// + lane*16B, which the GEMM staging pattern satisfies by construction.
#if __has_builtin(__builtin_amdgcn_global_load_lds)
#define G2L(gp, lp)                                                        \
  __builtin_amdgcn_global_load_lds(                                        \
      (const __attribute__((address_space(1))) unsigned int*)(gp),         \
      (__attribute__((address_space(3))) unsigned int*)(lp), 16, 0, 0)
#else
#define G2L(gp, lp) (*(uint4*)(lp) = *(const uint4*)(gp))
#endif

__device__ __forceinline__ unsigned short f2b(float f) {
  union { float fl; unsigned int i; } v; v.fl = f;
  unsigned int r = v.i + 0x7fffu + ((v.i >> 16) & 1u);  // RNE, non-NaN inputs
  return (unsigned short)(r >> 16);
}
// pack two f32 -> two bf16 (round-to-nearest): low16 = a, high16 = b
__device__ __forceinline__ unsigned int pack_bf16(float a, float b) {
  unsigned int ua = __float_as_uint(a) + 0x8000u;
  unsigned int ub = __float_as_uint(b) + 0x8000u;
  return (ua >> 16) | (ub & 0xffff0000u);
}
__device__ __forceinline__ float blo(unsigned int u) { return __uint_as_float(u << 16); }
__device__ __forceinline__ float bhi(unsigned int u) { return __uint_as_float(u & 0xffff0000u); }

// ---------------------------------------------------------------------------
// One-shot f32 -> bf16 convert of x|Wq|Wk|Wv|Wo into a contiguous bf16 blob.
// ---------------------------------------------------------------------------
__global__ __launch_bounds__(256) void cvt_kernel(
    const float* __restrict__ x,  const float* __restrict__ wq,
    const float* __restrict__ wk, const float* __restrict__ wv,
    const float* __restrict__ wo, unsigned short* __restrict__ dst)
{
  size_t i = ((size_t)blockIdx.x * 256 + threadIdx.x) * 8;
  const float* src; size_t off;
  if      (i <  8388608u) { src = x;  off = i; }
  else if (i <  9437184u) { src = wq; off = i - 8388608u; }
  else if (i <  9568256u) { src = wk; off = i - 9437184u; }
  else if (i <  9699328u) { src = wv; off = i - 9568256u; }
  else                    { src = wo; off = i - 9699328u; }
  float4 a = *(const float4*)(src + off);
  float4 b = *(const float4*)(src + off + 4);
  uint4 o;
  o.x = pack_bf16(a.x, a.y); o.y = pack_bf16(a.z, a.w);
  o.z = pack_bf16(b.x, b.y); o.w = pack_bf16(b.z, b.w);
  *(uint4*)(dst + i) = o;
}

// ---------------------------------------------------------------------------
// 128x128-tile GEMM body, C = A * B^T, K=1024, bf16 in, fp32 accumulate.
// global_load_lds staging into UNPADDED stride-32 LDS (lane-contiguous).
// ---------------------------------------------------------------------------
template <bool C_F32>
__device__ __forceinline__ void gemm_body_1024(
    const unsigned short* __restrict__ Arow0,
    const unsigned short* __restrict__ Btile,
    void* __restrict__ Cb, int ldC)
{
  __shared__ unsigned short As[128 * 32];
  __shared__ unsigned short Bs[128 * 32];
  const int tid = threadIdx.x;
  const int lane = tid & 63;
  const int w = tid >> 6;
  const int wr = w >> 1, wc = w & 1;
  const int l15 = lane & 15, quad = lane >> 4;

  const unsigned short* a_src = Arow0 + (size_t)(tid >> 2) * 1024 + (tid & 3) * 8;
  const unsigned short* b_src = Btile + (size_t)(tid >> 2) * 1024 + (tid & 3) * 8;
  unsigned short* a_dst = &As[(tid >> 2) * 32 + (tid & 3) * 8];
  unsigned short* b_dst = &Bs[(tid >> 2) * 32 + (tid & 3) * 8];

  floatx4 zero = {0.f, 0.f, 0.f, 0.f};
  floatx4 acc[4][4];
#pragma unroll
  for (int i = 0; i < 4; i++)
#pragma unroll
    for (int j = 0; j < 4; j++) acc[i][j] = zero;

  for (int k0 = 0; k0 < 1024; k0 += 32) {
    __syncthreads();
    G2L(a_src + k0,         a_dst);
    G2L(a_src + 65536 + k0, a_dst + 2048);   // +64 rows
    G2L(b_src + k0,         b_dst);
    G2L(b_src + 65536 + k0, b_dst + 2048);
    __syncthreads();                          // drains vmcnt incl. lds-DMA
    short8 af[4], bfr[4];
#pragma unroll
    for (int i = 0; i < 4; i++)
      af[i] = *(const short8*)&As[(wr * 64 + i * 16 + l15) * 32 + quad * 8];
#pragma unroll
    for (int j = 0; j < 4; j++)
      bfr[j] = *(const short8*)&Bs[(wc * 64 + j * 16 + l15) * 32 + quad * 8];
#pragma unroll
    for (int i = 0; i < 4; i++)
#pragma unroll
      for (int j = 0; j < 4; j++)
        acc[i][j] = __builtin_amdgcn_mfma_f32_16x16x32_bf16(af[i], bfr[j], acc[i][j], 0, 0, 0);
  }
  // epilogue: C row = quad*4+reg, col = lane&15 (verified m89/m91 layout)
#pragma unroll
  for (int i = 0; i < 4; i++)
#pragma unroll
    for (int j = 0; j < 4; j++)
#pragma unroll
      for (int r = 0; r < 4; r++) {
        size_t off = (size_t)(wr * 64 + i * 16 + quad * 4 + r) * ldC + wc * 64 + j * 16 + l15;
        if (C_F32) ((float*)Cb)[off] = acc[i][j][r];
        else ((unsigned short*)Cb)[off] = f2b(acc[i][j][r]);
      }
}

__global__ __launch_bounds__(256) void gemm_qkv_kernel(
    const unsigned short* __restrict__ x,
    const unsigned short* __restrict__ Wq,
    const unsigned short* __restrict__ Wk,
    const unsigned short* __restrict__ Wv,
    unsigned short* __restrict__ q,
    unsigned short* __restrict__ k,
    unsigned short* __restrict__ v)
{
  const int bx = blockIdx.x, by = blockIdx.y;
  const unsigned short* Btile;
  unsigned short* C;
  int ldC, col0;
  if (by < 8) { Btile = Wq + (size_t)by * 128 * 1024; C = q; ldC = 1024; col0 = by * 128; }
  else if (by == 8) { Btile = Wk; C = k; ldC = 128; col0 = 0; }
  else { Btile = Wv; C = v; ldC = 128; col0 = 0; }
  gemm_body_1024<false>(x + (size_t)bx * 128 * 1024, Btile,
                        C + (size_t)bx * 128 * ldC + col0, ldC);
}

__global__ __launch_bounds__(256) void gemm_out_kernel(
    const unsigned short* __restrict__ ao,
    const unsigned short* __restrict__ Wo,
    float* __restrict__ out)
{
  const int bx = blockIdx.x, by = blockIdx.y;
  gemm_body_1024<true>(ao + (size_t)bx * 128 * 1024, Wo + (size_t)by * 128 * 1024,
                       out + (size_t)bx * 128 * 1024 + by * 128, 1024);
}

// ---------------------------------------------------------------------------
// prep: fused vtrans (blocks 0..255) + vectorized RoPE (8 pairs/thread).
// q gets gain*(1/sqrt(HD))/SOFTCAP folded in.
// ---------------------------------------------------------------------------
__global__ __launch_bounds__(256) void prep_kernel(
    unsigned short* __restrict__ q,
    unsigned short* __restrict__ k,
    const unsigned short* __restrict__ v,
    unsigned short* __restrict__ vT,
    const float* __restrict__ cosT,
    const float* __restrict__ sinT,
    const float* __restrict__ gain)
{
  __shared__ unsigned short tile[32 * 136];
  const int tid = threadIdx.x;
  if (blockIdx.x < 256) {
    const int b = blockIdx.x >> 6, t0 = (blockIdx.x & 63) * 32;
    for (int u = tid; u < 512; u += 256) {
      int r = u >> 4, c = u & 15;
      *(uint4*)&tile[r * 136 + c * 8] =
          *(const uint4*)(v + ((size_t)(b * T_ + t0 + r)) * 128 + c * 8);
    }
    __syncthreads();
    for (int u = tid; u < 512; u += 256) {
      int d = u >> 2, c = u & 3;
      short8 val;
#pragma unroll
      for (int j = 0; j < 8; j++) val[j] = (short)tile[(c * 8 + j) * 136 + d];
      *(short8*)(vT + ((size_t)(b * 128 + d)) * T_ + t0 + c * 8) = val;
    }
    return;
  }
  int idx = (blockIdx.x - 256) * 256 + tid;   // 0 .. 589823
  unsigned short* ptr;
  size_t base;
  int t, j;
  float g;
  if (idx < 524288) {                         // q: (bt, h, dim-octet j)
    j = idx & 7;
    int h = (idx >> 3) & 7;
    int bt = idx >> 6;
    t = bt & (T_ - 1);
    base = (size_t)bt * 1024 + h * 128 + j * 8;
    ptr = q;
    g = gain[h] * 0.0029462782549439484f;     // (1/sqrt(128))/30
  } else {                                    // k
    int id = idx - 524288;
    j = id & 7;
    int bt = id >> 3;
    t = bt & (T_ - 1);
    base = (size_t)bt * 128 + j * 8;
    ptr = k;
    g = 1.f;
  }
  float4 ca = *(const float4*)&cosT[t * 64 + j * 8];
  float4 cb = *(const float4*)&cosT[t * 64 + j * 8 + 4];
  float4 sa = *(const float4*)&sinT[t * 64 + j * 8];
  float4 sb = *(const float4*)&sinT[t * 64 + j * 8 + 4];
  uint4 lo = *(const uint4*)(ptr + base);
  uint4 hi = *(const uint4*)(ptr + base + 64);
  uint4 olo, ohi;
  {
    float a0 = blo(lo.x), a1 = bhi(lo.x), b0 = blo(hi.x), b1 = bhi(hi.x);
    olo.x = pack_bf16((a0 * ca.x - b0 * sa.x) * g, (a1 * ca.y - b1 * sa.y) * g);
    ohi.x = pack_bf16((a0 * sa.x + b0 * ca.x) * g, (a1 * sa.y + b1 * ca.y) * g);
  }
  {
    float a0 = blo(lo.y), a1 = bhi(lo.y), b0 = blo(hi.y), b1 = bhi(hi.y);
    olo.y = pack_bf16((a0 * ca.z - b0 * sa.z) * g, (a1 * ca.w - b1 * sa.w) * g);
    ohi.y = pack_bf16((a0 * sa.z + b0 * ca.z) * g, (a1 * sa.w + b1 * ca.w) * g);
  }
  {
    float a0 = blo(lo.z), a1 = bhi(lo.z), b0 = blo(hi.z), b1 = bhi(hi.z);
    olo.z = pack_bf16((a0 * cb.x - b0 * sb.x) * g, (a1 * cb.y - b1 * sb.y) * g);
    ohi.z = pack_bf16((a0 * sb.x + b0 * cb.x) * g, (a1 * sb.y + b1 * cb.y) * g);
  }
  {
    float a0 = blo(lo.w), a1 = bhi(lo.w), b0 = blo(hi.w), b1 = bhi(hi.w);
    olo.w = pack_bf16((a0 * cb.z - b0 * sb.z) * g, (a1 * cb.w - b1 * sb.w) * g);
    ohi.w = pack_bf16((a0 * sb.z + b0 * cb.z) * g, (a1 * sb.w + b1 * cb.w) * g);
  }
  *(uint4*)(ptr + base) = olo;
  *(uint4*)(ptr + base + 64) = ohi;
}

// ---------------------------------------------------------------------------
// Flash attention. ROUND 12: 32x32x16 MFMA — 4x work per LDS byte.
// Rounds 1-3 all ~74us: per-CU LDS pipe ~80% busy (2.1M ds_read_b128 +
// 0.6M ds_write + 10.7M conflict-cycles at round-3 geometry). LDS is a
// per-CU resource, so occupancy couldn't help; reads-per-FLOP must drop.
// With mfma_f32_32x32x16_bf16 a wave owns 32 q-rows; per 32-key tile:
// 8 QK^T + 8 PV MFMA32 fed by 8 kf + 8 vf ds_read_b128 -> reads/work 4x
// lower than round 3, 2x lower than round 1; barriers/staging/shuffles per
// work also halve (128-row blocks). Existing Ks[16x264]/Vts[128x40] layouts
// already give baseline bank spread for the new frag reads (8 lanes/group).
//
// Fragment algebra (C/D layout col=lane&31, row=(reg&3)+8(reg>>2)+4hi,
// hi=lane>>5; A: row=lane&31,k=8hi+j; B: col=lane&31,k=8hi+j):
//  S^T[key][q] via mfma(kf, qf): lane holds P at q=lane&31,
//    key(r)=(r&3)+8(r>>2)+4hi, r=0..15.
//  Pack pairs -> dwords A0..A7: Am = keys {4hi+..} per the r-mapping.
//  PV B-frag needs k=8hi+j keys per half. Exactly 4 permlane32_swaps:
//    swap(A0,A2),swap(A1,A3) -> B0=[A0,A1,A2,A3] (keys 0-15)
//    swap(A4,A6),swap(A5,A7) -> B1=[A4,A5,A6,A7] (keys 16-31)
//  (swap: new_a={a_lo,b_lo}, new_b={a_hi,b_hi}; dword-exact, see round 10.)
// Registers ~155 (acc 64 AGPR + st 16 + qf 32 + misc) -> 3 waves/SIMD
// (__launch_bounds__(256,3)); NSPLIT=3 -> 768 blocks = 3 blocks/CU,
// LDS 112KB/CU. T14 issue-early/write-late staging retained.
// ---------------------------------------------------------------------------
template <int NSPLIT>
__global__ __launch_bounds__(256, 3) void attn_kernel(
    const unsigned short* __restrict__ q,
    const unsigned short* __restrict__ k,
    const unsigned short* __restrict__ vT,
    unsigned short* __restrict__ ao,
    unsigned short* __restrict__ Opart,
    float* __restrict__ lbuf)
{
  __shared__ unsigned short Ks[2][16 * 264];   // [buf][dimgroup d][key*8 + j]
  __shared__ unsigned short Vts[2][128 * 40];  // [buf][dim][key]

  const int h = blockIdx.y, b = blockIdx.z;
  const int pr   = blockIdx.x / NSPLIT;        // 0..7 (chunk-pair index)
  const int part = blockIdx.x % NSPLIT;
  const int tid = threadIdx.x, lane = tid & 63, w = tid >> 6;
  const int q32 = lane & 31, hi = lane >> 5;

  // K staging: key = tid>>4 (+16), dimgroup = tid&15
  const unsigned short* ksrc =
      k + (size_t)b * T_ * 128 + (size_t)(tid >> 4) * 128 + (tid & 15) * 8;
  const int koff0 = (tid & 15) * 264 + (tid >> 4) * 8;
  const int koff1 = koff0 + 16 * 8;
  // V staging: row = tid>>2 (+64), col8 = tid&3
  const unsigned short* vsrc =
      vT + (size_t)b * 128 * T_ + (size_t)(tid >> 2) * T_ + (tid & 3) * 8;
  const int voff0 = (tid >> 2) * 40 + (tid & 3) * 8;
  const int voff1 = voff0 + 64 * 40;

  for (int pass = 0; pass < 2; pass++) {
    const int qblock = pass ? (15 - pr) : pr;  // 128-row q-chunk index
    const int qw = qblock * 128 + w * 32;      // wave's first q-row
    const int nkt = 4 * qblock + 4;
    const int base = nkt / NSPLIT, rem = nkt % NSPLIT;
    const int ktBeg = part * base + (part < rem ? part : rem);
    const int ktEnd = ktBeg + base + (part < rem ? 1 : 0);

    // Q B-frags: lane holds Q[q=qw+q32][dim = c*16 + 8*hi + j], c=0..7
    short8 qf[8];
    {
      const unsigned short* qrow =
          q + ((size_t)(b * T_ + qw + q32) * NH_ + h) * HD_ + hi * 8;
#pragma unroll
      for (int c = 0; c < 8; c++) qf[c] = *(const short8*)(qrow + c * 16);
    }

    float l_i = 0.f;
    floatx16 acc[4];
#pragma unroll
    for (int dt = 0; dt < 4; dt++)
#pragma unroll
      for (int r = 0; r < 16; r++) acc[dt][r] = 0.f;

    // pass-start barrier: previous pass/prologue reads done before reuse
    __syncthreads();
    // prologue: stage tile ktBeg into buf[ktBeg&1]
    {
      uint4 kr0 = *(const uint4*)(ksrc + (size_t)ktBeg * 4096);
      uint4 kr1 = *(const uint4*)(ksrc + (size_t)ktBeg * 4096 + 2048);
      uint4 vr0 = *(const uint4*)(vsrc + ktBeg * 32);
      uint4 vr1 = *(const uint4*)(vsrc + (size_t)64 * T_ + ktBeg * 32);
      unsigned short* kb = Ks[ktBeg & 1];
      unsigned short* vb = Vts[ktBeg & 1];
      *(uint4*)(kb + koff0) = kr0; *(uint4*)(kb + koff1) = kr1;
      *(uint4*)(vb + voff0) = vr0; *(uint4*)(vb + voff1) = vr1;
    }

    for (int kt = ktBeg; kt < ktEnd; kt++) {
      __syncthreads();                 // publishes buf[kt&1]
      // prefetch tile kt+1 AFTER the barrier (T14): latency hides under
      // compute; write-late store consumes it before the next barrier.
      uint4 kr0, kr1, vr0, vr1;
      const bool more = (kt + 1 < ktEnd);
      if (more) {
        kr0 = *(const uint4*)(ksrc + (size_t)(kt + 1) * 4096);
        kr1 = *(const uint4*)(ksrc + (size_t)(kt + 1) * 4096 + 2048);
        vr0 = *(const uint4*)(vsrc + (kt + 1) * 32);
        vr1 = *(const uint4*)(vsrc + (size_t)64 * T_ + (kt + 1) * 32);
      }

      if (kt * 32 <= qw + 31) {        // wave-uniform causal skip
        const unsigned short* KsC = Ks[kt & 1];
        const unsigned short* VtC = Vts[kt & 1];
        // S^T = K Q^T, one 32x32 tile, K-dim = 128 = 8 chained MFMA32
        floatx16 st;
#pragma unroll
        for (int r = 0; r < 16; r++) st[r] = 0.f;
#pragma unroll
        for (int c = 0; c < 8; c++) {
          short8 kf = *(const short8*)&KsC[(2 * c + hi) * 264 + q32 * 8];
          st = __builtin_amdgcn_mfma_f32_32x32x16_bf16(kf, qf[c], st, 0, 0, 0);
        }
        // fused softcap+softmax numerator (fixed m=30), all in registers
        float rs = 0.f;
        unsigned int A[8];
        if (kt * 32 + 31 <= qw) {      // fully unmasked (most iterations)
          float pv[16];
#pragma unroll
          for (int r = 0; r < 16; r++) {
            float s = st[r];
            float e = EXP2F(2.8853901f * s);
            float u = RCPF(e + 1.f);
            float p = EXP2F(-86.561707f * u);
            pv[r] = p;
            rs += p;
          }
#pragma unroll
          for (int m = 0; m < 8; m++) A[m] = pack_bf16(pv[2 * m], pv[2 * m + 1]);
        } else {                       // boundary tile: apply causal mask
          const int qrow = qw + q32;
          float pv[16];
#pragma unroll
          for (int r = 0; r < 16; r++) {
            float s = st[r];
            float e = EXP2F(2.8853901f * s);
            float u = RCPF(e + 1.f);
            float p = EXP2F(-86.561707f * u);
            int key = kt * 32 + (r & 3) + 8 * (r >> 2) + 4 * hi;
            p = (key <= qrow) ? p : 0.f;
            pv[r] = p;
            rs += p;
          }
#pragma unroll
          for (int m = 0; m < 8; m++) A[m] = pack_bf16(pv[2 * m], pv[2 * m + 1]);
        }
        // build PV B-frags via 4 permlane32 swaps (see header derivation)
        unsigned int a0 = A[0], a1 = A[1], a2 = A[2], a3 = A[3];
        unsigned int a4 = A[4], a5 = A[5], a6 = A[6], a7 = A[7];
        asm("v_permlane32_swap_b32 %0, %1" : "+v"(a0), "+v"(a2));
        asm("v_permlane32_swap_b32 %0, %1" : "+v"(a1), "+v"(a3));
        asm("v_permlane32_swap_b32 %0, %1" : "+v"(a4), "+v"(a6));
        asm("v_permlane32_swap_b32 %0, %1" : "+v"(a5), "+v"(a7));
        uint4 u0; u0.x = a0; u0.y = a1; u0.z = a2; u0.w = a3;
        uint4 u1; u1.x = a4; u1.y = a5; u1.z = a6; u1.w = a7;
        short8 pf0 = *(short8*)&u0;   // keys 0-15 B-frag
        short8 pf1 = *(short8*)&u1;   // keys 16-31 B-frag
        l_i += rs + __shfl_xor(rs, 32);
        // O^T += V^T P^T: 4 d-tiles x 2 key-halves
#pragma unroll
        for (int dt = 0; dt < 4; dt++) {
          short8 v0 = *(const short8*)&VtC[(dt * 32 + q32) * 40 + hi * 8];
          short8 v1 = *(const short8*)&VtC[(dt * 32 + q32) * 40 + 16 + hi * 8];
          acc[dt] = __builtin_amdgcn_mfma_f32_32x32x16_bf16(v0, pf0, acc[dt], 0, 0, 0);
          acc[dt] = __builtin_amdgcn_mfma_f32_32x32x16_bf16(v1, pf1, acc[dt], 0, 0, 0);
        }
      }

      if (more) {                      // write-late: stage kt+1 after compute
        unsigned short* kb = Ks[(kt + 1) & 1];
        unsigned short* vb = Vts[(kt + 1) & 1];
        *(uint4*)(kb + koff0) = kr0; *(uint4*)(kb + koff1) = kr1;
        *(uint4*)(vb + voff0) = vr0; *(uint4*)(vb + voff1) = vr1;
      }
    }

    // epilogue: lane q=q32; acc[dt][r] = O^T[dim=dt*32+(r&3)+8(r>>2)+4hi][q]
    {
      const size_t rowidx = (size_t)(b * T_ + qw + q32) * NH_ + h;
      if (NSPLIT == 1) {
        float linv = 1.f / l_i;
        unsigned short* aop = ao + rowidx * HD_;
#pragma unroll
        for (int dt = 0; dt < 4; dt++)
#pragma unroll
          for (int rg = 0; rg < 4; rg++) {
            uint2 o;
            o.x = pack_bf16(acc[dt][4 * rg + 0] * linv, acc[dt][4 * rg + 1] * linv);
            o.y = pack_bf16(acc[dt][4 * rg + 2] * linv, acc[dt][4 * rg + 3] * linv);
            *(uint2*)(aop + dt * 32 + rg * 8 + hi * 4) = o;
          }
      } else {
        unsigned short* dst =
            ((part == NSPLIT - 1) ? ao : Opart + (size_t)part * 8388608u) +
            rowidx * HD_;
#pragma unroll
        for (int dt = 0; dt < 4; dt++)
#pragma unroll
          for (int rg = 0; rg < 4; rg++) {
            uint2 o;
            o.x = pack_bf16(acc[dt][4 * rg + 0], acc[dt][4 * rg + 1]);
            o.y = pack_bf16(acc[dt][4 * rg + 2], acc[dt][4 * rg + 3]);
            *(uint2*)(dst + dt * 32 + rg * 8 + hi * 4) = o;
          }
        if (hi == 0) lbuf[(size_t)part * 65536u + rowidx] = l_i;
      }
    }
  }
}

// ao = (sum of partials + ao) / (sum of l), 8 bf16 elems per thread
template <int NSPLIT>
__global__ __launch_bounds__(256) void combine_kernel(
    const unsigned short* __restrict__ Opart,
    const float* __restrict__ lbuf,
    unsigned short* __restrict__ ao)
{
  size_t i = ((size_t)blockIdx.x * 256 + threadIdx.x) * 8;
  size_t r = i >> 7;                          // (b*T+t)*NH+h
  float ls = 0.f;
#pragma unroll
  for (int p = 0; p < NSPLIT; p++) ls += lbuf[(size_t)p * 65536u + r];
  float linv = RCPF(ls);
  uint4 c = *(const uint4*)(ao + i);
  float v0 = blo(c.x), v1 = bhi(c.x), v2 = blo(c.y), v3 = bhi(c.y);
  float v4 = blo(c.z), v5 = bhi(c.z), v6 = blo(c.w), v7 = bhi(c.w);
#pragma unroll
  for (int p = 0; p < NSPLIT - 1; p++) {
    uint4 a = *(const uint4*)(Opart + (size_t)p * 8388608u + i);
    v0 += blo(a.x); v1 += bhi(a.x); v2 += blo(a.y); v3 += bhi(a.y);
    v4 += blo(a.z); v5 += bhi(a.z); v6 += blo(a.w); v7 += bhi(a.w);
  }
  uint4 o;
  o.x = pack_bf16(v0 * linv, v1 * linv);
  o.y = pack_bf16(v2 * linv, v3 * linv);
  o.z = pack_bf16(v4 * linv, v5 * linv);
  o.w = pack_bf16(v6 * linv, v7 * linv);
  *(uint4*)(ao + i) = o;
}

extern "C" void kernel_launch(void* const* d_in, const int* in_sizes, int n_in,
                              void* d_out, int out_size, void* d_ws, size_t ws_size,
                              hipStream_t stream) {
  const float* x    = (const float*)d_in[0];
  const float* Wq   = (const float*)d_in[1];
  const float* Wk   = (const float*)d_in[2];
  const float* Wv   = (const float*)d_in[3];
  const float* Wo   = (const float*)d_in[4];
  const float* gain = (const float*)d_in[5];
  const float* cosT = (const float*)d_in[6];
  const float* sinT = (const float*)d_in[7];
  float* out = (float*)d_out;

  unsigned short* ws = (unsigned short*)d_ws;  // elem offsets (bf16)
  unsigned short* blob = ws;                   // x|Wq|Wk|Wv|Wo bf16
  unsigned short* xb  = blob;
  unsigned short* Wqb = blob + 8388608u;
  unsigned short* Wkb = blob + 9437184u;
  unsigned short* Wvb = blob + 9568256u;
  unsigned short* Wob = blob + 9699328u;
  unsigned short* q   = ws + 10747904u;        // 8388608 elems
  unsigned short* kk  = ws + 19136512u;        // 1048576
  unsigned short* v   = ws + 20185088u;        // 1048576
  unsigned short* vT  = ws + 21233664u;        // 1048576
  unsigned short* ao  = xb;                    // alias: xb dead after gemm_qkv
  unsigned short* Opart = ws + 22282240u;      // up to 2 x 8388608 elems
  float* l2 = (float*)((char*)d_ws + 61341696u);   // 2 x 65536 f32
  const size_t need2 = 61865984ull;
  float* l3 = (float*)((char*)d_ws + 78118912u);   // 3 x 65536 f32
  const size_t need3 = 78905344ull;

  // 0. f32 -> bf16 convert of all GEMM operands
  cvt_kernel<<<5248, 256, 0, stream>>>(x, Wq, Wk, Wv, Wo, blob);
  // 1. fused QKV projection (M=8192, K=1024, N=1024+128+128)
  gemm_qkv_kernel<<<dim3(64, 10), 256, 0, stream>>>(xb, Wqb, Wkb, Wvb, q, kk, v);
  // 2. prep: vtrans (256 blocks) + vectorized RoPE (2304 blocks)
  prep_kernel<<<2560, 256, 0, stream>>>(q, kk, v, vT, cosT, sinT, gain);
  // 3. flash attention + combine. 128-row 4-wave blocks (32 q-rows/wave via
  //    32x32x16 MFMA), chunk pairs (pr, 15-pr) x NSPLIT=3 -> 768 blocks =
  //    3 blocks/CU, matching the 3 waves/SIMD register budget.
  if (ws_size >= need3) {
    attn_kernel<3><<<dim3(24, 8, 4), 256, 0, stream>>>(q, kk, vT, ao, Opart, l3);
    combine_kernel<3><<<4096, 256, 0, stream>>>(Opart, l3, ao);
  } else if (ws_size >= need2) {
    attn_kernel<2><<<dim3(16, 8, 4), 256, 0, stream>>>(q, kk, vT, ao, Opart, l2);
    combine_kernel<2><<<4096, 256, 0, stream>>>(Opart, l2, ao);
  } else {
    attn_kernel<1><<<dim3(8, 8, 4), 256, 0, stream>>>(q, kk, vT, ao, Opart, l2);
  }
  // 4. output projection (bf16 -> f32 out)
  gemm_out_kernel<<<dim3(64, 8), 256, 0, stream>>>(ao, Wob, out);
}